// Round 2
// baseline (3092.015 us; speedup 1.0000x reference)
//
#include <hip/hip_runtime.h>
#include <stdint.h>

typedef unsigned short u16;
typedef unsigned int u32;

// ---------- bf16 helpers (LDS-internal compression of q,k only) ----------
__device__ __forceinline__ u16 f2bf(float f) {
  union { float f; u32 u; } v; v.f = f;
  u32 u = v.u;
  return (u16)((u + 0x7fffu + ((u >> 16) & 1u)) >> 16);
}
__device__ __forceinline__ float bf2f_lo(u32 u) {
  union { u32 uu; float f; } v; v.uu = u << 16; return v.f;
}
__device__ __forceinline__ float bf2f_hi(u32 u) {
  union { u32 uu; float f; } v; v.uu = u & 0xffff0000u; return v.f;
}
__device__ __forceinline__ void cvt8(uint4 w, float* f) {
  f[0] = bf2f_lo(w.x); f[1] = bf2f_hi(w.x);
  f[2] = bf2f_lo(w.y); f[3] = bf2f_hi(w.y);
  f[4] = bf2f_lo(w.z); f[5] = bf2f_hi(w.z);
  f[6] = bf2f_lo(w.w); f[7] = bf2f_hi(w.w);
}

// ---------- constants ----------
#define NT 49        // tokens per window
#define CD 256       // dim
#define NWIN 4096    // 64 imgs * 64 windows
#define SA_RS 260    // sA row stride (f32): 256+4 -> lane-row stride 4 mod 32 banks
#define SB_RS 520    // sB row stride (bf16): q cols 0..255, k cols 256..511, +8 pad
#define SV_RS 260    // sV row stride (f32)

// =====================================================================
// Kernel A: CPB MLP: table[p*8+h] = relu(coords@w1^T + b1) @ w2^T  (f32 in)
// =====================================================================
__global__ void cpb_table_kernel(const float* __restrict__ coords,
                                 const float* __restrict__ w1,
                                 const float* __restrict__ b1,
                                 const float* __restrict__ w2,
                                 float* __restrict__ table) {
  int t = blockIdx.x * 256 + threadIdx.x;
  if (t >= 169 * 8) return;
  int p = t >> 3, h = t & 7;
  float c0 = coords[p * 2], c1 = coords[p * 2 + 1];
  float acc = 0.f;
  for (int j = 0; j < 512; ++j) {
    float hid = fmaf(c0, w1[j * 2], fmaf(c1, w1[j * 2 + 1], b1[j]));
    hid = fmaxf(hid, 0.f);
    acc = fmaf(hid, w2[h * 512 + j], acc);
  }
  table[t] = acc;  // t == p*8+h
}

// =====================================================================
// Kernel B: rpbT[h][j][i] = 16*sigmoid(table[rpi[i][j]][h])  (8*2401)
//           maskT[w][j][i] = mask[w][i][j]                    (64*2401)
// i-fast layouts so the attention score loop reads are lane-coalesced.
// =====================================================================
__global__ void bias_prep_kernel(const float* __restrict__ table,
                                 const int* __restrict__ rpi,
                                 const float* __restrict__ mask,
                                 float* __restrict__ rpbT,
                                 float* __restrict__ maskT) {
  int idx = blockIdx.x * 256 + threadIdx.x;
  if (idx < 8 * 2401) {
    int h = idx / 2401;
    int r = idx - h * 2401;
    int j = r / 49, i = r - j * 49;
    float v = table[rpi[i * 49 + j] * 8 + h];
    rpbT[idx] = 16.f / (1.f + __expf(-v));
  } else if (idx < 8 * 2401 + 64 * 2401) {
    int k = idx - 8 * 2401;
    int w = k / 2401;
    int r = k - w * 2401;
    int j = r / 49, i = r - j * 49;
    maskT[k] = mask[w * 2401 + i * 49 + j];
  }
}

// =====================================================================
// Fused per-window kernel (512 threads): qkv GEMM -> cosine attn -> proj
// =====================================================================
__global__ __launch_bounds__(512) void swin_fused(
    const float* __restrict__ x, const float* __restrict__ qkv_w,
    const float* __restrict__ q_bias, const float* __restrict__ v_bias,
    const float* __restrict__ logit_scale, const float* __restrict__ rpbT,
    const float* __restrict__ maskT,
    const float* __restrict__ proj_w, const float* __restrict__ proj_b,
    float* __restrict__ out) {
  __shared__ float sA[50 * SA_RS];  // x -> normalized K -> attn out (f32)
  __shared__ u16 sB[50 * SB_RS];    // q (cols 0..255), k (256..511) as bf16
  __shared__ float sV[50 * SV_RS];  // v (f32)

  const int tid = threadIdx.x;
  const int wid = blockIdx.x;
  const int wimg = wid & 63;

  // ---- Phase 1: x -> sA rows 0..48; zero row 49 ----
  {
    const float4* xg = (const float4*)(x + (size_t)wid * (NT * CD));
    for (int e = tid; e < (NT * CD) / 4; e += 512) {
      int row = e >> 6, c4 = e & 63;
      *(float4*)&sA[row * SA_RS + c4 * 4] = xg[e];
    }
    for (int e = tid; e < 64; e += 512)
      *(float4*)&sA[49 * SA_RS + e * 4] = make_float4(0.f, 0.f, 0.f, 0.f);
  }
  __syncthreads();

  // ---- Phase 2: qkv = x @ qkv_w^T + bias; q,k -> sB (bf16), v -> sV (f32) ----
  {
    const int c = tid & 255;   // output column within each of q/k/v
    const int ih = tid >> 8;   // row half: rows ih*25 .. ih*25+24 (row 49 zeroed)
    const int i0 = ih * 25;
    float accq[25], acck[25], accv[25];
    const float bq = q_bias[c], bv = v_bias[c];
#pragma unroll
    for (int ii = 0; ii < 25; ++ii) { accq[ii] = bq; acck[ii] = 0.f; accv[ii] = bv; }
    const float4* wq = (const float4*)(qkv_w + (size_t)c * 256);
    const float4* wk = (const float4*)(qkv_w + (size_t)(256 + c) * 256);
    const float4* wv = (const float4*)(qkv_w + (size_t)(512 + c) * 256);
    float4 aq = wq[0], ak = wk[0], av = wv[0];
    for (int k4 = 0; k4 < 64; ++k4) {
      float4 nq, nk, nv;
      if (k4 < 63) { nq = wq[k4 + 1]; nk = wk[k4 + 1]; nv = wv[k4 + 1]; }
#pragma unroll
      for (int ii = 0; ii < 25; ++ii) {
        float4 xv = *(const float4*)&sA[(i0 + ii) * SA_RS + k4 * 4];
        float q0 = accq[ii], k0 = acck[ii], v0 = accv[ii];
        q0 = fmaf(aq.x, xv.x, q0); q0 = fmaf(aq.y, xv.y, q0);
        q0 = fmaf(aq.z, xv.z, q0); q0 = fmaf(aq.w, xv.w, q0);
        k0 = fmaf(ak.x, xv.x, k0); k0 = fmaf(ak.y, xv.y, k0);
        k0 = fmaf(ak.z, xv.z, k0); k0 = fmaf(ak.w, xv.w, k0);
        v0 = fmaf(av.x, xv.x, v0); v0 = fmaf(av.y, xv.y, v0);
        v0 = fmaf(av.z, xv.z, v0); v0 = fmaf(av.w, xv.w, v0);
        accq[ii] = q0; acck[ii] = k0; accv[ii] = v0;
      }
      aq = nq; ak = nk; av = nv;
    }
#pragma unroll
    for (int ii = 0; ii < 25; ++ii) {
      const int row = i0 + ii;  // row 49: zeros -> finite garbage, never read
      sB[row * SB_RS + c] = f2bf(accq[ii]);
      sB[row * SB_RS + 256 + c] = f2bf(acck[ii]);
      sV[row * SV_RS + c] = accv[ii];
    }
  }
  __syncthreads();

  // ---- Phase 3: per (head, row) task; head uniform per wave ----
  const int hh = tid >> 6;        // head 0..7
  const int il = tid & 63;        // row, active if < 49
  const bool act = il < NT;

  // 3a: normalized K -> sA (overwrites x)
  if (act) {
    const uint4* kb = (const uint4*)&sB[il * SB_RS + 256 + hh * 32];
    float kf[32];
#pragma unroll
    for (int cgrp = 0; cgrp < 4; ++cgrp) { uint4 t4 = kb[cgrp]; cvt8(t4, &kf[cgrp * 8]); }
    float ss = 1e-6f;
#pragma unroll
    for (int d = 0; d < 32; ++d) ss = fmaf(kf[d], kf[d], ss);
    const float rk = rsqrtf(ss);
    float4* dst = (float4*)&sA[il * SA_RS + hh * 32];
#pragma unroll
    for (int cgrp = 0; cgrp < 8; ++cgrp)
      dst[cgrp] = make_float4(kf[cgrp * 4] * rk, kf[cgrp * 4 + 1] * rk,
                              kf[cgrp * 4 + 2] * rk, kf[cgrp * 4 + 3] * rk);
  }
  __syncthreads();

  // 3b: scores + softmax (p stays in registers across the barrier)
  float p[49];
  float inv = 0.f;
  if (act) {
    const float scl = __expf(fminf(logit_scale[hh], 4.605170186f));
    const uint4* qb = (const uint4*)&sB[il * SB_RS + hh * 32];
    float qf[32];
#pragma unroll
    for (int cgrp = 0; cgrp < 4; ++cgrp) { uint4 t4 = qb[cgrp]; cvt8(t4, &qf[cgrp * 8]); }
    float ss = 1e-6f;
#pragma unroll
    for (int d = 0; d < 32; ++d) ss = fmaf(qf[d], qf[d], ss);
    const float qs = rsqrtf(ss) * scl;
#pragma unroll
    for (int d = 0; d < 32; ++d) qf[d] *= qs;
    const float* rpb_b = rpbT + hh * 2401 + il;
    const float* msk_b = maskT + wimg * 2401 + il;
    float mx = -1e30f;
#pragma unroll
    for (int j = 0; j < 49; ++j) {
      const float4* kr = (const float4*)&sA[j * SA_RS + hh * 32];
      float s0 = 0.f, s1 = 0.f, s2 = 0.f, s3 = 0.f;
#pragma unroll
      for (int cgrp = 0; cgrp < 8; ++cgrp) {
        float4 kv = kr[cgrp];
        s0 = fmaf(qf[cgrp * 4 + 0], kv.x, s0);
        s1 = fmaf(qf[cgrp * 4 + 1], kv.y, s1);
        s2 = fmaf(qf[cgrp * 4 + 2], kv.z, s2);
        s3 = fmaf(qf[cgrp * 4 + 3], kv.w, s3);
      }
      float pv = (s0 + s1) + (s2 + s3) + rpb_b[j * 49] + msk_b[j * 49];
      p[j] = pv;
      mx = fmaxf(mx, pv);
    }
    float sum = 0.f;
#pragma unroll
    for (int j = 0; j < 49; ++j) { float e = __expf(p[j] - mx); p[j] = e; sum += e; }
    inv = 1.0f / sum;
  }
  __syncthreads();  // all kn reads done before attn-out overwrites sA

  // 3c: attn-out = (p/sum) @ v -> sA
  if (act) {
    float o[32];
#pragma unroll
    for (int d = 0; d < 32; ++d) o[d] = 0.f;
    for (int j = 0; j < 49; ++j) {
      const float4* vb = (const float4*)&sV[j * SV_RS + hh * 32];
      const float pj = p[j];
#pragma unroll
      for (int cgrp = 0; cgrp < 8; ++cgrp) {
        float4 vv = vb[cgrp];
        o[cgrp * 4 + 0] = fmaf(pj, vv.x, o[cgrp * 4 + 0]);
        o[cgrp * 4 + 1] = fmaf(pj, vv.y, o[cgrp * 4 + 1]);
        o[cgrp * 4 + 2] = fmaf(pj, vv.z, o[cgrp * 4 + 2]);
        o[cgrp * 4 + 3] = fmaf(pj, vv.w, o[cgrp * 4 + 3]);
      }
    }
    float4* dst = (float4*)&sA[il * SA_RS + hh * 32];
#pragma unroll
    for (int cgrp = 0; cgrp < 8; ++cgrp)
      dst[cgrp] = make_float4(o[cgrp * 4] * inv, o[cgrp * 4 + 1] * inv,
                              o[cgrp * 4 + 2] * inv, o[cgrp * 4 + 3] * inv);
  }
  __syncthreads();

  // ---- Phase 4: out = attn_out @ proj_w^T + proj_b ----
  {
    const int c = tid & 255;
    const int ih = tid >> 8;
    const int i0 = ih * 25;
    float acc[25];
    const float bp = proj_b[c];
#pragma unroll
    for (int ii = 0; ii < 25; ++ii) acc[ii] = bp;
    const float4* wp = (const float4*)(proj_w + (size_t)c * 256);
    float4 a = wp[0];
    for (int k4 = 0; k4 < 64; ++k4) {
      float4 na;
      if (k4 < 63) na = wp[k4 + 1];
#pragma unroll
      for (int ii = 0; ii < 25; ++ii) {
        float4 xv = *(const float4*)&sA[(i0 + ii) * SA_RS + k4 * 4];
        float a0 = acc[ii];
        a0 = fmaf(a.x, xv.x, a0); a0 = fmaf(a.y, xv.y, a0);
        a0 = fmaf(a.z, xv.z, a0); a0 = fmaf(a.w, xv.w, a0);
        acc[ii] = a0;
      }
      a = na;
    }
    float* og = out + (size_t)wid * (NT * CD);
#pragma unroll
    for (int ii = 0; ii < 25; ++ii) {
      const int row = i0 + ii;
      if (ih == 0 || ii < 24)  // row < 49
        og[row * 256 + c] = acc[ii];
    }
  }
}

extern "C" void kernel_launch(void* const* d_in, const int* in_sizes, int n_in,
                              void* d_out, int out_size, void* d_ws, size_t ws_size,
                              hipStream_t stream) {
  (void)in_sizes; (void)n_in; (void)out_size; (void)ws_size;
  const float* x           = (const float*)d_in[0];
  const float* qkv_w       = (const float*)d_in[1];
  const float* q_bias      = (const float*)d_in[2];
  const float* v_bias      = (const float*)d_in[3];
  const float* logit_scale = (const float*)d_in[4];
  const float* cpb_w1      = (const float*)d_in[5];
  const float* cpb_b1      = (const float*)d_in[6];
  const float* cpb_w2      = (const float*)d_in[7];
  const float* coords      = (const float*)d_in[8];
  const int*   rpi         = (const int*)d_in[9];
  const float* mask        = (const float*)d_in[10];
  const float* proj_w      = (const float*)d_in[11];
  const float* proj_b      = (const float*)d_in[12];
  float* out = (float*)d_out;

  float* table = (float*)d_ws;                      // 169*8 f32 (5.4 KB)
  float* rpbT  = (float*)((char*)d_ws + 8192);      // 8*2401 f32 (76.8 KB)
  float* maskT = (float*)((char*)d_ws + 8192 + 80000); // 64*2401 f32 (614 KB)

  hipLaunchKernelGGL(cpb_table_kernel, dim3(6), dim3(256), 0, stream,
                     coords, cpb_w1, cpb_b1, cpb_w2, table);
  hipLaunchKernelGGL(bias_prep_kernel, dim3((8 * 2401 + 64 * 2401 + 255) / 256),
                     dim3(256), 0, stream, table, rpi, mask, rpbT, maskT);
  hipLaunchKernelGGL(swin_fused, dim3(NWIN), dim3(512), 0, stream,
                     x, qkv_w, q_bias, v_bias, logit_scale, rpbT, maskT,
                     proj_w, proj_b, out);
}